// Round 1
// baseline (200.393 us; speedup 1.0000x reference)
//
#include <hip/hip_runtime.h>
#include <hip/hip_bf16.h>

typedef __bf16 bf16x8 __attribute__((ext_vector_type(8)));
typedef float f32x4 __attribute__((ext_vector_type(4)));

#define BATCH 65536
#define NL 256   // N_LSTM
#define NZ 1024  // 4*N_LSTM
#define FEAT 5

__device__ __forceinline__ unsigned short f2bf(float f) {
  __hip_bfloat16 h = __float2bfloat16(f);  // RTNE
  return __builtin_bit_cast(unsigned short, h);
}

// U [256][1024] f32  ->  Ut [1024][256] bf16 (transposed, so B-fragments are k-contiguous)
__global__ __launch_bounds__(256) void k_prep(const float* __restrict__ U,
                                              unsigned short* __restrict__ Ut) {
  __shared__ float t[32][33];
  const int bk = blockIdx.x >> 5;  // 0..7   (k tile of 32)
  const int bn = blockIdx.x & 31;  // 0..31  (n tile of 32)
  const int r = threadIdx.x >> 5;  // 0..7
  const int c = threadIdx.x & 31;  // 0..31
#pragma unroll
  for (int i = 0; i < 4; ++i)
    t[r + 8 * i][c] = U[(size_t)(bk * 32 + r + 8 * i) * NZ + bn * 32 + c];
  __syncthreads();
#pragma unroll
  for (int i = 0; i < 4; ++i)
    Ut[(size_t)(bn * 32 + r + 8 * i) * NL + bk * 32 + c] = f2bf(t[c][r + 8 * i]);
}

// Fused: z = x@W + h0@U + b ; gates ; c,h ; logits = h@Wd + bd
// Block: 64 batch rows, 512 threads = 8 waves.
// Wave w owns gate-cols [32w, 32w+32) for ALL 4 gate chunks (n = 256g + 32w + ...),
// so zi/zf/zc/zo for one (m,j) sit in the same lane & reg -> fusion is register-only.
__global__ __launch_bounds__(512, 2) void k_lstm(
    const float* __restrict__ x,    // [B][5]
    const float* __restrict__ h0,   // [B][256]
    const float* __restrict__ c0,   // [B][256]
    const float* __restrict__ W,    // [5][1024]
    const float* __restrict__ b,    // [1024]
    const float* __restrict__ Wd,   // [256][5]
    const float* __restrict__ bd,   // [5]
    const unsigned short* __restrict__ Ut,  // [1024][256] bf16
    float* __restrict__ out) {
  float* out_logits = out;
  float* out_h = out + (size_t)BATCH * FEAT;
  float* out_c = out_h + (size_t)BATCH * NL;

  __shared__ __align__(16) unsigned short A_sh[64 * 256];  // 32 KB bf16, XOR-swizzled
  __shared__ __align__(16) float h_sh[64 * 260];           // 66.5 KB (+4 pad per row)
  __shared__ float x_sh[64 * FEAT];

  const int tid = threadIdx.x;
  const int w = tid >> 6;  // wave 0..7
  const int l = tid & 63;
  const int m0 = blockIdx.x * 64;

  if (tid < 64 * FEAT) x_sh[tid] = x[(size_t)m0 * FEAT + tid];

  // Stage A = h0 tile [64][256] f32 -> bf16 LDS, swizzle elem ^= (row&7)<<3
#pragma unroll
  for (int it = 0; it < 8; ++it) {
    const int fi = it * 512 + tid;  // float4 index
    const int row = fi >> 6;
    const int c4 = fi & 63;
    const float4 v =
        *reinterpret_cast<const float4*>(h0 + (size_t)(m0 + row) * NL + c4 * 4);
    const ushort4 q = make_ushort4(f2bf(v.x), f2bf(v.y), f2bf(v.z), f2bf(v.w));
    const int elem = (row * 256 + c4 * 4) ^ ((row & 7) << 3);
    *reinterpret_cast<ushort4*>(&A_sh[elem]) = q;
  }
  __syncthreads();

  f32x4 acc[4][4][2];  // [r: 16-row tile][g: gate][t: 16-col tile]
#pragma unroll
  for (int r = 0; r < 4; ++r)
#pragma unroll
    for (int g = 0; g < 4; ++g)
#pragma unroll
      for (int t = 0; t < 2; ++t) acc[r][g][t] = (f32x4){0.f, 0.f, 0.f, 0.f};

  const int lrow = l & 15;
  const int lk8 = (l >> 4) * 8;

  for (int kk = 0; kk < 8; ++kk) {  // K = 256 in steps of 32
    const int k0 = kk * 32;
    bf16x8 af[4];
#pragma unroll
    for (int r = 0; r < 4; ++r) {
      const int row = r * 16 + lrow;
      const int elem = (row * 256 + k0 + lk8) ^ ((row & 7) << 3);
      af[r] = *reinterpret_cast<const bf16x8*>(&A_sh[elem]);
    }
#pragma unroll
    for (int g = 0; g < 4; ++g)
#pragma unroll
      for (int t = 0; t < 2; ++t) {
        const int n = g * 256 + w * 32 + t * 16 + lrow;
        const bf16x8 bfr =
            *reinterpret_cast<const bf16x8*>(Ut + (size_t)n * NL + k0 + lk8);
#pragma unroll
        for (int r = 0; r < 4; ++r)
          acc[r][g][t] =
              __builtin_amdgcn_mfma_f32_16x16x32_bf16(af[r], bfr, acc[r][g][t], 0, 0, 0);
      }
  }

  // Epilogue: z = acc + b + x@W (exact f32), gates, c/h, stores
  const int lq = (l >> 4) * 4;
#pragma unroll
  for (int t = 0; t < 2; ++t) {
    const int jcol = w * 32 + t * 16 + lrow;  // gate col 0..255
    float bb[4], ww[4][FEAT];
#pragma unroll
    for (int g = 0; g < 4; ++g) {
      const int n = g * 256 + jcol;
      bb[g] = b[n];
#pragma unroll
      for (int f = 0; f < FEAT; ++f) ww[g][f] = W[(size_t)f * NZ + n];
    }
#pragma unroll
    for (int r = 0; r < 4; ++r) {
#pragma unroll
      for (int v = 0; v < 4; ++v) {
        const int mloc = r * 16 + lq + v;
        const size_t m = (size_t)m0 + mloc;
        float zi = acc[r][0][t][v] + bb[0];
        float zf = acc[r][1][t][v] + bb[1];
        float zc = acc[r][2][t][v] + bb[2];
        float zo = acc[r][3][t][v] + bb[3];
#pragma unroll
        for (int f = 0; f < FEAT; ++f) {
          const float xf = x_sh[mloc * FEAT + f];
          zi += xf * ww[0][f];
          zf += xf * ww[1][f];
          zc += xf * ww[2][f];
          zo += xf * ww[3][f];
        }
        const float ig = 1.f / (1.f + __expf(-zi));
        const float fg = 1.f / (1.f + __expf(-zf));
        const float og = 1.f / (1.f + __expf(-zo));
        const float rc = zc > 0.f ? zc : 0.f;
        const float cv = fg * c0[m * NL + jcol] + ig * rc;
        const float hv = og * (cv > 0.f ? cv : 0.f);
        out_c[m * NL + jcol] = cv;
        out_h[m * NL + jcol] = hv;
        h_sh[mloc * 260 + jcol] = hv;
      }
    }
  }
  __syncthreads();

  // logits = h @ Wd + bd  (64 rows x 5 outs = 320 threads)
  if (tid < 64 * FEAT) {
    const int mloc = tid / FEAT;
    const int p = tid % FEAT;
    float s = bd[p];
#pragma unroll 8
    for (int j4 = 0; j4 < 64; ++j4) {
      const float4 hv = *reinterpret_cast<const float4*>(&h_sh[mloc * 260 + j4 * 4]);
      const int j = j4 * 4;
      s += hv.x * Wd[(size_t)j * FEAT + p] + hv.y * Wd[(size_t)(j + 1) * FEAT + p] +
           hv.z * Wd[(size_t)(j + 2) * FEAT + p] + hv.w * Wd[(size_t)(j + 3) * FEAT + p];
    }
    out_logits[(size_t)(m0 + mloc) * FEAT + p] = s;
  }
}

extern "C" void kernel_launch(void* const* d_in, const int* in_sizes, int n_in,
                              void* d_out, int out_size, void* d_ws, size_t ws_size,
                              hipStream_t stream) {
  const float* x = (const float*)d_in[0];   // seq_in [65536][1][5]
  const float* h0 = (const float*)d_in[1];  // [65536][256]
  const float* c0 = (const float*)d_in[2];  // [65536][256]
  const float* W = (const float*)d_in[3];   // [5][1024]
  const float* U = (const float*)d_in[4];   // [256][1024]
  const float* b = (const float*)d_in[5];   // [1024]
  const float* Wd = (const float*)d_in[6];  // [256][5]
  const float* bd = (const float*)d_in[7];  // [5]
  unsigned short* Ut = (unsigned short*)d_ws;  // 1024*256*2 = 512 KB

  k_prep<<<256, 256, 0, stream>>>(U, Ut);
  k_lstm<<<BATCH / 64, 512, 0, stream>>>(x, h0, c0, W, b, Wd, bd, Ut, (float*)d_out);
}

// Round 2
// 182.014 us; speedup vs baseline: 1.1010x; 1.1010x over previous
//
#include <hip/hip_runtime.h>
#include <hip/hip_bf16.h>

typedef __bf16 bf16x8 __attribute__((ext_vector_type(8)));
typedef float f32x4 __attribute__((ext_vector_type(4)));

#define BATCH 65536
#define NL 256   // N_LSTM
#define NZ 1024  // 4*N_LSTM
#define FEAT 5
#define ROWS 32  // batch rows per block

__device__ __forceinline__ unsigned short f2bf(float f) {
  __hip_bfloat16 h = __float2bfloat16(f);  // RTNE
  return __builtin_bit_cast(unsigned short, h);
}

// U [256][1024] f32  ->  Ut [1024][256] bf16 (transposed: B-fragments k-contiguous)
__global__ __launch_bounds__(256) void k_prep(const float* __restrict__ U,
                                              unsigned short* __restrict__ Ut) {
  __shared__ float t[32][33];
  const int bk = blockIdx.x >> 5;  // k tile
  const int bn = blockIdx.x & 31;  // n tile
  const int r = threadIdx.x >> 5;
  const int c = threadIdx.x & 31;
#pragma unroll
  for (int i = 0; i < 4; ++i)
    t[r + 8 * i][c] = U[(size_t)(bk * 32 + r + 8 * i) * NZ + bn * 32 + c];
  __syncthreads();
#pragma unroll
  for (int i = 0; i < 4; ++i)
    Ut[(size_t)(bn * 32 + r + 8 * i) * NL + bk * 32 + c] = f2bf(t[c][r + 8 * i]);
}

// Block: 32 batch rows, 512 threads = 8 waves, 2048 blocks.
// Wave w owns gate-cols jmod256 in [32w,32w+32) for ALL 4 gates -> gate fusion
// is register-only. acc = 64 f32/thread; LDS ~18KB -> target 4 waves/SIMD.
__global__ __launch_bounds__(512, 4) void k_lstm(
    const float* __restrict__ x,    // [B][5]
    const float* __restrict__ h0,   // [B][256]
    const float* __restrict__ c0,   // [B][256]
    const float* __restrict__ W,    // [5][1024]
    const float* __restrict__ b,    // [1024]
    const float* __restrict__ Wd,   // [256][5]
    const float* __restrict__ bd,   // [5]
    const unsigned short* __restrict__ Ut,  // [1024][256] bf16
    float* __restrict__ out) {
  float* out_logits = out;
  float* out_h = out + (size_t)BATCH * FEAT;
  float* out_c = out_h + (size_t)BATCH * NL;

  __shared__ __align__(16) unsigned short A_sh[ROWS * 256];  // 16 KB, XOR-swizzled
  __shared__ float x_sh[ROWS * FEAT];
  __shared__ float lg[ROWS * FEAT];  // logits accumulator

  const int tid = threadIdx.x;
  const int w = tid >> 6;  // wave 0..7
  const int l = tid & 63;
  const int m0 = blockIdx.x * ROWS;

  if (tid < ROWS * FEAT) {
    x_sh[tid] = x[(size_t)m0 * FEAT + tid];
    lg[tid] = 0.f;
  }

  // Stage A = h0 tile [32][256] f32 -> bf16 LDS, swizzle elem ^= (row&7)<<3
#pragma unroll
  for (int it = 0; it < 4; ++it) {
    const int fi = it * 512 + tid;  // float4 index
    const int row = fi >> 6;
    const int c4 = fi & 63;
    const float4 v =
        *reinterpret_cast<const float4*>(h0 + (size_t)(m0 + row) * NL + c4 * 4);
    const ushort4 q = make_ushort4(f2bf(v.x), f2bf(v.y), f2bf(v.z), f2bf(v.w));
    const int elem = (row * 256 + c4 * 4) ^ ((row & 7) << 3);
    *reinterpret_cast<ushort4*>(&A_sh[elem]) = q;
  }
  __syncthreads();

  f32x4 acc[2][4][2];  // [r: 16-row tile][g: gate][t: 16-col tile]
#pragma unroll
  for (int r = 0; r < 2; ++r)
#pragma unroll
    for (int g = 0; g < 4; ++g)
#pragma unroll
      for (int t = 0; t < 2; ++t) acc[r][g][t] = (f32x4){0.f, 0.f, 0.f, 0.f};

  const int lrow = l & 15;
  const int lk8 = (l >> 4) * 8;

#pragma unroll 2
  for (int kk = 0; kk < 8; ++kk) {  // K = 256 in steps of 32
    const int k0 = kk * 32;
    bf16x8 af[2];
#pragma unroll
    for (int r = 0; r < 2; ++r) {
      const int row = r * 16 + lrow;
      const int elem = (row * 256 + k0 + lk8) ^ ((row & 7) << 3);
      af[r] = *reinterpret_cast<const bf16x8*>(&A_sh[elem]);
    }
#pragma unroll
    for (int g = 0; g < 4; ++g)
#pragma unroll
      for (int t = 0; t < 2; ++t) {
        const int n = g * 256 + w * 32 + t * 16 + lrow;
        const bf16x8 bfr =
            *reinterpret_cast<const bf16x8*>(Ut + (size_t)n * NL + k0 + lk8);
#pragma unroll
        for (int r = 0; r < 2; ++r)
          acc[r][g][t] =
              __builtin_amdgcn_mfma_f32_16x16x32_bf16(af[r], bfr, acc[r][g][t], 0, 0, 0);
      }
  }

  // Epilogue: z = acc + b + x@W (exact f32), gates, c/h stores, logits partials
  const int lq = (l >> 4) * 4;
#pragma unroll
  for (int t = 0; t < 2; ++t) {
    const int jcol = w * 32 + t * 16 + lrow;  // gate col 0..255
    float bb[4], ww[4][FEAT], wd[FEAT];
#pragma unroll
    for (int g = 0; g < 4; ++g) {
      const int n = g * 256 + jcol;
      bb[g] = b[n];
#pragma unroll
      for (int f = 0; f < FEAT; ++f) ww[g][f] = W[(size_t)f * NZ + n];
    }
#pragma unroll
    for (int p = 0; p < FEAT; ++p) wd[p] = Wd[(size_t)jcol * FEAT + p];

#pragma unroll
    for (int r = 0; r < 2; ++r) {
#pragma unroll
      for (int v = 0; v < 4; ++v) {
        const int mloc = r * 16 + lq + v;
        const size_t m = (size_t)m0 + mloc;
        float zi = acc[r][0][t][v] + bb[0];
        float zf = acc[r][1][t][v] + bb[1];
        float zc = acc[r][2][t][v] + bb[2];
        float zo = acc[r][3][t][v] + bb[3];
#pragma unroll
        for (int f = 0; f < FEAT; ++f) {
          const float xf = x_sh[mloc * FEAT + f];
          zi += xf * ww[0][f];
          zf += xf * ww[1][f];
          zc += xf * ww[2][f];
          zo += xf * ww[3][f];
        }
        const float ig = 1.f / (1.f + __expf(-zi));
        const float fg = 1.f / (1.f + __expf(-zf));
        const float og = 1.f / (1.f + __expf(-zo));
        const float rc = zc > 0.f ? zc : 0.f;
        const float cv = fg * c0[m * NL + jcol] + ig * rc;
        const float hv = og * (cv > 0.f ? cv : 0.f);
        out_c[m * NL + jcol] = cv;
        out_h[m * NL + jcol] = hv;

        // logits partial: sum over jcol (16 lanes of this lrow-group)
        float pp[FEAT];
#pragma unroll
        for (int p = 0; p < FEAT; ++p) pp[p] = hv * wd[p];
#pragma unroll
        for (int p = 0; p < FEAT; ++p) {
          pp[p] += __shfl_xor(pp[p], 1);
          pp[p] += __shfl_xor(pp[p], 2);
          pp[p] += __shfl_xor(pp[p], 4);
          pp[p] += __shfl_xor(pp[p], 8);
        }
        if (lrow == 0) {
#pragma unroll
          for (int p = 0; p < FEAT; ++p) atomicAdd(&lg[mloc * FEAT + p], pp[p]);
        }
      }
    }
  }
  __syncthreads();

  if (tid < ROWS * FEAT) {
    out_logits[(size_t)m0 * FEAT + tid] = lg[tid] + bd[tid % FEAT];
  }
}

extern "C" void kernel_launch(void* const* d_in, const int* in_sizes, int n_in,
                              void* d_out, int out_size, void* d_ws, size_t ws_size,
                              hipStream_t stream) {
  const float* x = (const float*)d_in[0];   // seq_in [65536][1][5]
  const float* h0 = (const float*)d_in[1];  // [65536][256]
  const float* c0 = (const float*)d_in[2];  // [65536][256]
  const float* W = (const float*)d_in[3];   // [5][1024]
  const float* U = (const float*)d_in[4];   // [256][1024]
  const float* b = (const float*)d_in[5];   // [1024]
  const float* Wd = (const float*)d_in[6];  // [256][5]
  const float* bd = (const float*)d_in[7];  // [5]
  unsigned short* Ut = (unsigned short*)d_ws;  // 1024*256*2 = 512 KB

  k_prep<<<256, 256, 0, stream>>>(U, Ut);
  k_lstm<<<BATCH / ROWS, 512, 0, stream>>>(x, h0, c0, W, b, Wd, bd, Ut, (float*)d_out);
}

// Round 3
// 150.723 us; speedup vs baseline: 1.3295x; 1.2076x over previous
//
#include <hip/hip_runtime.h>
#include <hip/hip_bf16.h>

typedef __bf16 bf16x8 __attribute__((ext_vector_type(8)));
typedef float f32x4 __attribute__((ext_vector_type(4)));

#define BATCH 65536
#define NL 256    // N_LSTM
#define NZ 1024   // 4*N_LSTM
#define FEAT 5
#define ROWS 32   // batch rows per block
#define KTOT 288  // 256 (h@U) + 32 (x@W folded, 5 real + 27 zero)
#define ASTRIDE 296  // A_sh row stride in bf16 elems (592B -> 20-bank rotation/row)

__device__ __forceinline__ unsigned short f2bf(float f) {
  __hip_bfloat16 h = __float2bfloat16(f);  // RTNE
  return __builtin_bit_cast(unsigned short, h);
}

// U [256][1024] f32 -> Ut [1024][288] bf16 rows 0..255 (transposed, k-contiguous)
__global__ __launch_bounds__(256) void k_prep(const float* __restrict__ U,
                                              unsigned short* __restrict__ Ut) {
  __shared__ float t[32][33];
  const int bk = blockIdx.x >> 5;  // k tile
  const int bn = blockIdx.x & 31;  // n tile
  const int r = threadIdx.x >> 5;
  const int c = threadIdx.x & 31;
#pragma unroll
  for (int i = 0; i < 4; ++i)
    t[r + 8 * i][c] = U[(size_t)(bk * 32 + r + 8 * i) * NZ + bn * 32 + c];
  __syncthreads();
#pragma unroll
  for (int i = 0; i < 4; ++i)
    Ut[(size_t)(bn * 32 + r + 8 * i) * KTOT + bk * 32 + c] = f2bf(t[c][r + 8 * i]);
}

// Fill Ut k-rows 256..287: [W (5 rows); zeros (27 rows)] transposed.
__global__ __launch_bounds__(1024) void k_prepx(const float* __restrict__ W,
                                                unsigned short* __restrict__ Ut) {
  const int idx = blockIdx.x * 1024 + threadIdx.x;  // 32768 entries
  const int n = idx >> 5;
  const int cc = idx & 31;
  Ut[(size_t)n * KTOT + 256 + cc] = (cc < FEAT) ? f2bf(W[(size_t)cc * NZ + n]) : (unsigned short)0;
}

// 1024 threads = 16 waves; wave w owns gate-cols jcol = w*16+lrow for all 4 gates.
// acc = 32 f32/thread (AGPR) -> ~96 arch VGPRs free for pipelining at 4 waves/SIMD.
__global__ __launch_bounds__(1024, 4) void k_lstm(
    const float* __restrict__ x,    // [B][5]
    const float* __restrict__ h0,   // [B][256]
    const float* __restrict__ c0,   // [B][256]
    const float* __restrict__ b,    // [1024]
    const float* __restrict__ Wd,   // [256][5]
    const float* __restrict__ bd,   // [5]
    const unsigned short* __restrict__ Ut,  // [1024][288] bf16
    float* __restrict__ out) {
  float* out_logits = out;
  float* out_h = out + (size_t)BATCH * FEAT;
  float* out_c = out_h + (size_t)BATCH * NL;

  __shared__ __align__(16) unsigned short A_sh[ROWS * ASTRIDE];  // 18.9 KB
  __shared__ float wd_sh[NL * FEAT];                             // 5 KB

  const int tid = threadIdx.x;
  const int w = tid >> 6;   // wave 0..15
  const int l = tid & 63;
  const int lrow = l & 15;
  const int lk8 = (l >> 4) * 8;
  const int lq = (l >> 4) * 4;
  const int m0 = blockIdx.x * ROWS;

  // ---- stage A tile: h0 [32][256] f32 -> bf16 cols 0..255
#pragma unroll
  for (int it = 0; it < 2; ++it) {
    const int fi = it * 1024 + tid;  // float4 index, 2048 total
    const int row = fi >> 6;
    const int c4 = fi & 63;
    const float4 v =
        *reinterpret_cast<const float4*>(h0 + (size_t)(m0 + row) * NL + c4 * 4);
    const ushort4 q = make_ushort4(f2bf(v.x), f2bf(v.y), f2bf(v.z), f2bf(v.w));
    *reinterpret_cast<ushort4*>(&A_sh[row * ASTRIDE + c4 * 4]) = q;
  }
  // x block: cols 256..287 = [x (5), zeros]
  {
    const int row = tid >> 5;
    const int cc = tid & 31;
    unsigned short v = 0;
    if (cc < FEAT) v = f2bf(x[(size_t)(m0 + row) * FEAT + cc]);
    A_sh[row * ASTRIDE + 256 + cc] = v;
  }
  // Wd -> LDS
  if (tid < NL * FEAT) wd_sh[tid] = Wd[tid];
  if (tid + 1024 < NL * FEAT) wd_sh[tid + 1024] = Wd[tid + 1024];
  __syncthreads();

  // ---- k-loop with register double-buffered B
  f32x4 acc[2][4];
#pragma unroll
  for (int r = 0; r < 2; ++r)
#pragma unroll
    for (int g = 0; g < 4; ++g) acc[r][g] = (f32x4){0.f, 0.f, 0.f, 0.f};

  const int ncol = w * 16 + lrow;  // this lane's B row (gate-col base)
  const unsigned short* bp0 = Ut + (size_t)(0 * 256 + ncol) * KTOT + lk8;
  const unsigned short* bp1 = Ut + (size_t)(1 * 256 + ncol) * KTOT + lk8;
  const unsigned short* bp2 = Ut + (size_t)(2 * 256 + ncol) * KTOT + lk8;
  const unsigned short* bp3 = Ut + (size_t)(3 * 256 + ncol) * KTOT + lk8;

  bf16x8 bcur[4], bnxt[4];
  bcur[0] = *reinterpret_cast<const bf16x8*>(bp0);
  bcur[1] = *reinterpret_cast<const bf16x8*>(bp1);
  bcur[2] = *reinterpret_cast<const bf16x8*>(bp2);
  bcur[3] = *reinterpret_cast<const bf16x8*>(bp3);

#pragma unroll
  for (int kk = 0; kk < 9; ++kk) {
    if (kk < 8) {
      const int k0n = (kk + 1) * 32;
      bnxt[0] = *reinterpret_cast<const bf16x8*>(bp0 + k0n);
      bnxt[1] = *reinterpret_cast<const bf16x8*>(bp1 + k0n);
      bnxt[2] = *reinterpret_cast<const bf16x8*>(bp2 + k0n);
      bnxt[3] = *reinterpret_cast<const bf16x8*>(bp3 + k0n);
    }
    bf16x8 af[2];
#pragma unroll
    for (int r = 0; r < 2; ++r)
      af[r] = *reinterpret_cast<const bf16x8*>(
          &A_sh[(r * 16 + lrow) * ASTRIDE + kk * 32 + lk8]);
#pragma unroll
    for (int g = 0; g < 4; ++g) {
      acc[0][g] = __builtin_amdgcn_mfma_f32_16x16x32_bf16(af[0], bcur[g], acc[0][g], 0, 0, 0);
      acc[1][g] = __builtin_amdgcn_mfma_f32_16x16x32_bf16(af[1], bcur[g], acc[1][g], 0, 0, 0);
    }
#pragma unroll
    for (int g = 0; g < 4; ++g) bcur[g] = bnxt[g];
  }

  // ---- epilogue: gates, c/h, stores (x@W already inside acc via k-block 8)
  const int jcol = ncol;  // gate col 0..255
  float bb[4];
#pragma unroll
  for (int g = 0; g < 4; ++g) bb[g] = b[g * 256 + jcol];

  float c0v[2][4];  // prefetch c0 (8 independent loads in flight)
#pragma unroll
  for (int r = 0; r < 2; ++r)
#pragma unroll
    for (int v = 0; v < 4; ++v)
      c0v[r][v] = c0[(size_t)(m0 + r * 16 + lq + v) * NL + jcol];

  float hv_reg[2][4];
#pragma unroll
  for (int r = 0; r < 2; ++r) {
#pragma unroll
    for (int v = 0; v < 4; ++v) {
      const size_t m = (size_t)m0 + r * 16 + lq + v;
      const float zi = acc[r][0][v] + bb[0];
      const float zf = acc[r][1][v] + bb[1];
      const float zc = acc[r][2][v] + bb[2];
      const float zo = acc[r][3][v] + bb[3];
      const float ig = 1.f / (1.f + __expf(-zi));
      const float fg = 1.f / (1.f + __expf(-zf));
      const float og = 1.f / (1.f + __expf(-zo));
      const float rc = fmaxf(zc, 0.f);
      const float cv = fg * c0v[r][v] + ig * rc;
      const float hv = og * fmaxf(cv, 0.f);
      out_c[m * NL + jcol] = cv;
      out_h[m * NL + jcol] = hv;
      hv_reg[r][v] = hv;
    }
  }

  // ---- logits: write h (bf16) into A_sh, then 160-thread LDS GEMV
  __syncthreads();  // all k-loop A_sh reads done
#pragma unroll
  for (int r = 0; r < 2; ++r)
#pragma unroll
    for (int v = 0; v < 4; ++v)
      A_sh[(r * 16 + lq + v) * ASTRIDE + jcol] = f2bf(hv_reg[r][v]);
  __syncthreads();

  if (tid < ROWS * FEAT) {
    const int mloc = tid / FEAT;
    const int p = tid % FEAT;
    float s = bd[p];
#pragma unroll
    for (int j8 = 0; j8 < 32; ++j8) {
      const bf16x8 hv8 = *reinterpret_cast<const bf16x8*>(&A_sh[mloc * ASTRIDE + j8 * 8]);
#pragma unroll
      for (int e = 0; e < 8; ++e)
        s += (float)hv8[e] * wd_sh[(j8 * 8 + e) * FEAT + p];
    }
    out_logits[(size_t)(m0 + mloc) * FEAT + p] = s;
  }
}

extern "C" void kernel_launch(void* const* d_in, const int* in_sizes, int n_in,
                              void* d_out, int out_size, void* d_ws, size_t ws_size,
                              hipStream_t stream) {
  const float* x = (const float*)d_in[0];   // seq_in [65536][1][5]
  const float* h0 = (const float*)d_in[1];  // [65536][256]
  const float* c0 = (const float*)d_in[2];  // [65536][256]
  const float* W = (const float*)d_in[3];   // [5][1024]
  const float* U = (const float*)d_in[4];   // [256][1024]
  const float* b = (const float*)d_in[5];   // [1024]
  const float* Wd = (const float*)d_in[6];  // [256][5]
  const float* bd = (const float*)d_in[7];  // [5]
  unsigned short* Ut = (unsigned short*)d_ws;  // 1024*288*2 = 576 KB

  k_prep<<<256, 256, 0, stream>>>(U, Ut);
  k_prepx<<<32, 1024, 0, stream>>>(W, Ut);
  k_lstm<<<BATCH / ROWS, 1024, 0, stream>>>(x, h0, c0, b, Wd, bd, Ut, (float*)d_out);
}

// Round 4
// 142.147 us; speedup vs baseline: 1.4098x; 1.0603x over previous
//
#include <hip/hip_runtime.h>
#include <hip/hip_bf16.h>

typedef __bf16 bf16x8 __attribute__((ext_vector_type(8)));
typedef float f32x4 __attribute__((ext_vector_type(4)));

#define BATCH 65536
#define NL 256    // N_LSTM
#define NZ 1024   // 4*N_LSTM
#define FEAT 5
#define ROWS 32   // batch rows per block
#define KTOT 288  // 256 (h@U) + 32 (x@W folded: 5 real + 27 zero)
#define ASTRIDE 296  // A_sh row stride (bf16 elems); 592B -> rotated banks, <=2-way
#define WDSTR 264    // WdT_sh row stride (bf16 elems); 528B -> rotated banks

__device__ __forceinline__ unsigned short f2bf(float f) {
  __hip_bfloat16 h = __float2bfloat16(f);  // RTNE
  return __builtin_bit_cast(unsigned short, h);
}

// U [256][1024] f32 -> Ut [1024][288] bf16 rows k=0..255 (transposed, k-contiguous)
__global__ __launch_bounds__(256) void k_prep(const float* __restrict__ U,
                                              unsigned short* __restrict__ Ut) {
  __shared__ float t[32][33];
  const int bk = blockIdx.x >> 5;
  const int bn = blockIdx.x & 31;
  const int r = threadIdx.x >> 5;
  const int c = threadIdx.x & 31;
#pragma unroll
  for (int i = 0; i < 4; ++i)
    t[r + 8 * i][c] = U[(size_t)(bk * 32 + r + 8 * i) * NZ + bn * 32 + c];
  __syncthreads();
#pragma unroll
  for (int i = 0; i < 4; ++i)
    Ut[(size_t)(bn * 32 + r + 8 * i) * KTOT + bk * 32 + c] = f2bf(t[c][r + 8 * i]);
}

// Ut k-rows 256..287: [W (5 rows); zeros (27 rows)] transposed.
__global__ __launch_bounds__(1024) void k_prepx(const float* __restrict__ W,
                                                unsigned short* __restrict__ Ut) {
  const int idx = blockIdx.x * 1024 + threadIdx.x;  // 32768
  const int n = idx >> 5;
  const int cc = idx & 31;
  Ut[(size_t)n * KTOT + 256 + cc] = (cc < FEAT) ? f2bf(W[(size_t)cc * NZ + n]) : (unsigned short)0;
}

// 1024 threads = 16 waves; wave w owns gate-col jcol = w*16+lrow for all 4 gates.
__global__ __launch_bounds__(1024, 4) void k_lstm(
    const float* __restrict__ x,    // [B][5]
    const float* __restrict__ h0,   // [B][256]
    const float* __restrict__ c0,   // [B][256]
    const float* __restrict__ b,    // [1024]
    const float* __restrict__ Wd,   // [256][5]
    const float* __restrict__ bd,   // [5]
    const unsigned short* __restrict__ Ut,  // [1024][288] bf16
    float* __restrict__ out) {
  float* out_logits = out;
  float* out_h = out + (size_t)BATCH * FEAT;
  float* out_c = out_h + (size_t)BATCH * NL;

  __shared__ __align__(16) unsigned short A_sh[ROWS * ASTRIDE];   // 18.9 KB
  __shared__ __align__(16) unsigned short WdT_sh[16 * WDSTR];     // 8.25 KB

  const int tid = threadIdx.x;
  const int w = tid >> 6;   // wave 0..15
  const int l = tid & 63;
  const int lrow = l & 15;
  const int lk8 = (l >> 4) * 8;
  const int lq = (l >> 4) * 4;
  const int m0 = blockIdx.x * ROWS;

  // ---- stage A tile: h0 [32][256] f32 -> bf16 cols 0..255
#pragma unroll
  for (int it = 0; it < 2; ++it) {
    const int fi = it * 1024 + tid;  // float4 index
    const int row = fi >> 6;
    const int c4 = fi & 63;
    const float4 v =
        *reinterpret_cast<const float4*>(h0 + (size_t)(m0 + row) * NL + c4 * 4);
    const ushort4 q = make_ushort4(f2bf(v.x), f2bf(v.y), f2bf(v.z), f2bf(v.w));
    *reinterpret_cast<ushort4*>(&A_sh[row * ASTRIDE + c4 * 4]) = q;
  }
  // x block: cols 256..287 = [x (5), zeros]
  {
    const int row = tid >> 5;
    const int cc = tid & 31;
    unsigned short v = 0;
    if (cc < FEAT) v = f2bf(x[(size_t)(m0 + row) * FEAT + cc]);
    A_sh[row * ASTRIDE + 256 + cc] = v;
  }
  // WdT_sh[p][j] = Wd[j][p], p padded 5->16 with zeros
#pragma unroll
  for (int e = 0; e < 4; ++e) {
    const int idx = e * 1024 + tid;  // 4096 entries
    const int p = idx >> 8;
    const int j = idx & 255;
    WdT_sh[p * WDSTR + j] = (p < FEAT) ? f2bf(Wd[(size_t)j * FEAT + p]) : (unsigned short)0;
  }
  __syncthreads();

  const int jcol = w * 16 + lrow;  // gate col 0..255

  // ---- early scalar loads: hide latency under the whole k-loop
  float bb[4];
#pragma unroll
  for (int g = 0; g < 4; ++g) bb[g] = b[g * 256 + jcol];
  float c0v[2][4];
#pragma unroll
  for (int r = 0; r < 2; ++r)
#pragma unroll
    for (int v = 0; v < 4; ++v)
      c0v[r][v] = c0[(size_t)(m0 + r * 16 + lq + v) * NL + jcol];

  // ---- k-loop: 2-deep rotating register prefetch of B
  f32x4 acc[2][4];
#pragma unroll
  for (int r = 0; r < 2; ++r)
#pragma unroll
    for (int g = 0; g < 4; ++g) acc[r][g] = (f32x4){0.f, 0.f, 0.f, 0.f};

  const unsigned short* bp[4];
#pragma unroll
  for (int g = 0; g < 4; ++g) bp[g] = Ut + (size_t)(g * 256 + jcol) * KTOT + lk8;

  bf16x8 bbuf[3][4];
#pragma unroll
  for (int g = 0; g < 4; ++g) bbuf[0][g] = *reinterpret_cast<const bf16x8*>(bp[g]);
#pragma unroll
  for (int g = 0; g < 4; ++g) bbuf[1][g] = *reinterpret_cast<const bf16x8*>(bp[g] + 32);

#pragma unroll
  for (int kk = 0; kk < 9; ++kk) {
    if (kk < 7) {
#pragma unroll
      for (int g = 0; g < 4; ++g)
        bbuf[(kk + 2) % 3][g] =
            *reinterpret_cast<const bf16x8*>(bp[g] + (kk + 2) * 32);
    }
    const bf16x8 af0 =
        *reinterpret_cast<const bf16x8*>(&A_sh[lrow * ASTRIDE + kk * 32 + lk8]);
    const bf16x8 af1 =
        *reinterpret_cast<const bf16x8*>(&A_sh[(16 + lrow) * ASTRIDE + kk * 32 + lk8]);
#pragma unroll
    for (int g = 0; g < 4; ++g) {
      acc[0][g] = __builtin_amdgcn_mfma_f32_16x16x32_bf16(af0, bbuf[kk % 3][g], acc[0][g], 0, 0, 0);
      acc[1][g] = __builtin_amdgcn_mfma_f32_16x16x32_bf16(af1, bbuf[kk % 3][g], acc[1][g], 0, 0, 0);
    }
  }

  __syncthreads();  // all k-loop A_sh reads done before h overwrites

  // ---- epilogue: gates, c/h stores, h -> A_sh (bf16) for logits MFMA
#pragma unroll
  for (int r = 0; r < 2; ++r) {
#pragma unroll
    for (int v = 0; v < 4; ++v) {
      const int mloc = r * 16 + lq + v;
      const size_t m = (size_t)m0 + mloc;
      const float zi = acc[r][0][v] + bb[0];
      const float zf = acc[r][1][v] + bb[1];
      const float zc = acc[r][2][v] + bb[2];
      const float zo = acc[r][3][v] + bb[3];
      const float ig = 1.f / (1.f + __expf(-zi));
      const float fg = 1.f / (1.f + __expf(-zf));
      const float og = 1.f / (1.f + __expf(-zo));
      const float rc = fmaxf(zc, 0.f);
      const float cv = fg * c0v[r][v] + ig * rc;
      const float hv = og * fmaxf(cv, 0.f);
      out_c[m * NL + jcol] = cv;
      out_h[m * NL + jcol] = hv;
      A_sh[mloc * ASTRIDE + jcol] = f2bf(hv);
    }
  }
  __syncthreads();

  // ---- logits = h @ Wd + bd via MFMA: waves 0,1 only; 8 chained MFMAs each
  if (w < 2) {
    f32x4 lacc = (f32x4){0.f, 0.f, 0.f, 0.f};
#pragma unroll
    for (int kk = 0; kk < 8; ++kk) {
      const bf16x8 ah = *reinterpret_cast<const bf16x8*>(
          &A_sh[(w * 16 + lrow) * ASTRIDE + kk * 32 + lk8]);
      const bf16x8 bw = *reinterpret_cast<const bf16x8*>(
          &WdT_sh[lrow * WDSTR + kk * 32 + lk8]);
      lacc = __builtin_amdgcn_mfma_f32_16x16x32_bf16(ah, bw, lacc, 0, 0, 0);
    }
    if (lrow < FEAT) {
      const float bdv = bd[lrow];
#pragma unroll
      for (int v = 0; v < 4; ++v)
        out_logits[(size_t)(m0 + w * 16 + lq + v) * FEAT + lrow] = lacc[v] + bdv;
    }
  }
}

extern "C" void kernel_launch(void* const* d_in, const int* in_sizes, int n_in,
                              void* d_out, int out_size, void* d_ws, size_t ws_size,
                              hipStream_t stream) {
  const float* x = (const float*)d_in[0];   // seq_in [65536][1][5]
  const float* h0 = (const float*)d_in[1];  // [65536][256]
  const float* c0 = (const float*)d_in[2];  // [65536][256]
  const float* W = (const float*)d_in[3];   // [5][1024]
  const float* U = (const float*)d_in[4];   // [256][1024]
  const float* b = (const float*)d_in[5];   // [1024]
  const float* Wd = (const float*)d_in[6];  // [256][5]
  const float* bd = (const float*)d_in[7];  // [5]
  unsigned short* Ut = (unsigned short*)d_ws;  // 1024*288*2 = 576 KB

  k_prep<<<256, 256, 0, stream>>>(U, Ut);
  k_prepx<<<32, 1024, 0, stream>>>(W, Ut);
  k_lstm<<<BATCH / ROWS, 1024, 0, stream>>>(x, h0, c0, b, Wd, bd, Ut, (float*)d_out);
}